// Round 2
// baseline (3329.527 us; speedup 1.0000x reference)
//
#include <hip/hip_runtime.h>

#define NPTS 8192
#define KN   32
#define DIM  256
#define DH   128
#define DOUT 512

// One block per query point n. 256 threads; thread c owns output channel c of
// every chained GEMM. Softmax is over the neighbor axis (k) per channel, so
// each thread softmaxes its own 32 registers -- no cross-lane traffic at all.
// All fp32 (reference dtype).
extern "C" __global__ __launch_bounds__(256, 2)
void ctb_fused(const float* __restrict__ xyz_q,
               const float* __restrict__ feats_q,
               const float* __restrict__ xyz_kv,
               const float* __restrict__ feats_kv,
               const float* __restrict__ Wq,
               const float* __restrict__ Wk,
               const float* __restrict__ Wv,
               const float* __restrict__ d1w, const float* __restrict__ d1b,
               const float* __restrict__ d2w, const float* __restrict__ d2b,
               const float* __restrict__ g1w, const float* __restrict__ g1b,
               const float* __restrict__ g2w, const float* __restrict__ g2b,
               const float* __restrict__ ow,  const float* __restrict__ ob,
               float* __restrict__ out)
{
    const int n = blockIdx.x;
    const int c = threadIdx.x;

    __shared__ __align__(16) float s_fkv[KN][DIM];   // 32 KB, feats_kv[n]
    __shared__ __align__(16) float s_buf[KN][DIM];   // 32 KB, r1 -> h -> t1
    __shared__ __align__(16) float s_q[DIM];
    __shared__ __align__(16) float s_rel[KN][4];
    __shared__ __align__(16) float s_res[DIM];

    // ---------------- load ----------------
    const float* fkv = feats_kv + (size_t)n * (KN * DIM);
    #pragma unroll 4
    for (int r = 0; r < KN; ++r)
        s_fkv[r][c] = fkv[r * DIM + c];
    s_q[c] = feats_q[(size_t)n * DIM + c];
    if (c < KN * 3) {
        const int k = c / 3, j = c - 3 * k;
        s_rel[k][j] = xyz_q[n * 3 + j] - xyz_kv[((size_t)n * KN + k) * 3 + j];
    }
    if (c < 3) out[n * 3 + c] = xyz_q[n * 3 + c];   // xyz passthrough (output 0)
    __syncthreads();

    // ------- pos MLP layer 1: relu(rel @ d1w + d1b) -> s_buf as [KN][DH] -------
    float* s_r1 = &s_buf[0][0];
    if (c < DH) {
        const float w0 = d1w[0 * DH + c];
        const float w1 = d1w[1 * DH + c];
        const float w2 = d1w[2 * DH + c];
        const float b  = d1b[c];
        #pragma unroll
        for (int k = 0; k < KN; ++k) {
            const float a = fmaf(s_rel[k][0], w0,
                            fmaf(s_rel[k][1], w1,
                            fmaf(s_rel[k][2], w2, b)));
            s_r1[k * DH + c] = fmaxf(a, 0.f);
        }
    }
    __syncthreads();

    // ------- pos MLP layer 2: pos[k] = r1[k] @ d2w[:,c] + d2b[c] -------
    float pos[KN];
    {
        const float b = d2b[c];
        #pragma unroll
        for (int k = 0; k < KN; ++k) pos[k] = b;
        for (int i = 0; i < DH; i += 4) {
            const float w0 = d2w[(i + 0) * DIM + c];
            const float w1 = d2w[(i + 1) * DIM + c];
            const float w2 = d2w[(i + 2) * DIM + c];
            const float w3 = d2w[(i + 3) * DIM + c];
            #pragma unroll
            for (int k = 0; k < KN; ++k) {
                const float4 f = *(const float4*)(s_r1 + k * DH + i);
                pos[k] = fmaf(f.x, w0, fmaf(f.y, w1,
                         fmaf(f.z, w2, fmaf(f.w, w3, pos[k]))));
            }
        }
    }

    // ------- q_attn[c] = feats_q[n] @ Wq[:,c] -------
    float qa = 0.f;
    for (int i = 0; i < DIM; i += 4) {
        const float4 f = *(const float4*)&s_q[i];
        qa = fmaf(f.x, Wq[(i + 0) * DIM + c],
             fmaf(f.y, Wq[(i + 1) * DIM + c],
             fmaf(f.z, Wq[(i + 2) * DIM + c],
             fmaf(f.w, Wq[(i + 3) * DIM + c], qa))));
    }

    // ------- k_attn[k][c] = feats_kv[n,k] @ Wk[:,c] -------
    float kk[KN];
    #pragma unroll
    for (int k = 0; k < KN; ++k) kk[k] = 0.f;
    for (int i = 0; i < DIM; i += 4) {
        const float w0 = Wk[(i + 0) * DIM + c];
        const float w1 = Wk[(i + 1) * DIM + c];
        const float w2 = Wk[(i + 2) * DIM + c];
        const float w3 = Wk[(i + 3) * DIM + c];
        #pragma unroll
        for (int k = 0; k < KN; ++k) {
            const float4 f = *(const float4*)&s_fkv[k][i];
            kk[k] = fmaf(f.x, w0, fmaf(f.y, w1,
                    fmaf(f.z, w2, fmaf(f.w, w3, kk[k]))));
        }
    }

    __syncthreads();   // all reads of s_r1 region done before h overwrites it
    // ------- h = q_attn - k_attn + pos -> s_buf -------
    #pragma unroll
    for (int k = 0; k < KN; ++k)
        s_buf[k][c] = qa - kk[k] + pos[k];
    __syncthreads();

    // ------- g1: t[k][c] = relu(h[k] @ g1w[:,c] + g1b[c]) -------
    float tt[KN];
    {
        const float b = g1b[c];
        #pragma unroll
        for (int k = 0; k < KN; ++k) tt[k] = b;
        for (int i = 0; i < DIM; i += 4) {
            const float w0 = g1w[(i + 0) * DIM + c];
            const float w1 = g1w[(i + 1) * DIM + c];
            const float w2 = g1w[(i + 2) * DIM + c];
            const float w3 = g1w[(i + 3) * DIM + c];
            #pragma unroll
            for (int k = 0; k < KN; ++k) {
                const float4 f = *(const float4*)&s_buf[k][i];
                tt[k] = fmaf(f.x, w0, fmaf(f.y, w1,
                        fmaf(f.z, w2, fmaf(f.w, w3, tt[k]))));
            }
        }
        #pragma unroll
        for (int k = 0; k < KN; ++k) tt[k] = fmaxf(tt[k], 0.f);
    }
    __syncthreads();
    #pragma unroll
    for (int k = 0; k < KN; ++k)
        s_buf[k][c] = tt[k];
    __syncthreads();

    // ------- g2: ap[k][c] = t[k] @ g2w[:,c] + g2b[c] -------
    float ap[KN];
    {
        const float b = g2b[c];
        #pragma unroll
        for (int k = 0; k < KN; ++k) ap[k] = b;
        for (int i = 0; i < DIM; i += 4) {
            const float w0 = g2w[(i + 0) * DIM + c];
            const float w1 = g2w[(i + 1) * DIM + c];
            const float w2 = g2w[(i + 2) * DIM + c];
            const float w3 = g2w[(i + 3) * DIM + c];
            #pragma unroll
            for (int k = 0; k < KN; ++k) {
                const float4 f = *(const float4*)&s_buf[k][i];
                ap[k] = fmaf(f.x, w0, fmaf(f.y, w1,
                        fmaf(f.z, w2, fmaf(f.w, w3, ap[k]))));
            }
        }
    }

    // ------- v_attn[k][c] = feats_kv[n,k] @ Wv[:,c] -------
    float vv[KN];
    #pragma unroll
    for (int k = 0; k < KN; ++k) vv[k] = 0.f;
    for (int i = 0; i < DIM; i += 4) {
        const float w0 = Wv[(i + 0) * DIM + c];
        const float w1 = Wv[(i + 1) * DIM + c];
        const float w2 = Wv[(i + 2) * DIM + c];
        const float w3 = Wv[(i + 3) * DIM + c];
        #pragma unroll
        for (int k = 0; k < KN; ++k) {
            const float4 f = *(const float4*)&s_fkv[k][i];
            vv[k] = fmaf(f.x, w0, fmaf(f.y, w1,
                    fmaf(f.z, w2, fmaf(f.w, w3, vv[k]))));
        }
    }

    // ------- softmax over k (per channel, all in registers) + weighted sum -------
    float m = ap[0];
    #pragma unroll
    for (int k = 1; k < KN; ++k) m = fmaxf(m, ap[k]);
    float ssum = 0.f, racc = 0.f;
    #pragma unroll
    for (int k = 0; k < KN; ++k) {
        const float e = __expf(ap[k] - m);
        ssum += e;
        racc = fmaf(e, vv[k] + pos[k], racc);
    }
    s_res[c] = racc / ssum;
    __syncthreads();

    // ------- out = res @ out_w + out_b (thread c -> channels c, c+256) -------
    {
        float o0 = ob[c];
        float o1 = ob[c + 256];
        for (int i = 0; i < DIM; i += 4) {
            const float4 f = *(const float4*)&s_res[i];
            o0 = fmaf(f.x, ow[(i + 0) * DOUT + c],
                 fmaf(f.y, ow[(i + 1) * DOUT + c],
                 fmaf(f.z, ow[(i + 2) * DOUT + c],
                 fmaf(f.w, ow[(i + 3) * DOUT + c], o0))));
            o1 = fmaf(f.x, ow[(i + 0) * DOUT + c + 256],
                 fmaf(f.y, ow[(i + 1) * DOUT + c + 256],
                 fmaf(f.z, ow[(i + 2) * DOUT + c + 256],
                 fmaf(f.w, ow[(i + 3) * DOUT + c + 256], o1))));
        }
        float* o = out + (size_t)NPTS * 3 + (size_t)n * DOUT;
        o[c]       = o0;
        o[c + 256] = o1;
    }
}

extern "C" void kernel_launch(void* const* d_in, const int* in_sizes, int n_in,
                              void* d_out, int out_size, void* d_ws, size_t ws_size,
                              hipStream_t stream) {
    const float* xyz_q    = (const float*)d_in[0];
    const float* feats_q  = (const float*)d_in[1];
    const float* xyz_kv   = (const float*)d_in[2];
    const float* feats_kv = (const float*)d_in[3];
    const float* Wq       = (const float*)d_in[4];
    const float* Wk       = (const float*)d_in[5];
    const float* Wv       = (const float*)d_in[6];
    const float* d1w      = (const float*)d_in[7];
    const float* d1b      = (const float*)d_in[8];
    const float* d2w      = (const float*)d_in[9];
    const float* d2b      = (const float*)d_in[10];
    const float* g1w      = (const float*)d_in[11];
    const float* g1b      = (const float*)d_in[12];
    const float* g2w      = (const float*)d_in[13];
    const float* g2b      = (const float*)d_in[14];
    const float* ow       = (const float*)d_in[15];
    const float* ob       = (const float*)d_in[16];
    float* out = (float*)d_out;

    ctb_fused<<<dim3(NPTS), dim3(256), 0, stream>>>(
        xyz_q, feats_q, xyz_kv, feats_kv, Wq, Wk, Wv,
        d1w, d1b, d2w, d2b, g1w, g1b, g2w, g2b, ow, ob, out);
}

// Round 3
// 1059.959 us; speedup vs baseline: 3.1412x; 3.1412x over previous
//
#include <hip/hip_runtime.h>
#include <hip/hip_bf16.h>

#define NPTS 8192
#define KN   32
#define DIM  256
#define DH   128
#define DOUT 512

typedef __attribute__((ext_vector_type(8))) short bf16x8;
typedef __attribute__((ext_vector_type(4))) float f32x4;

#define MFMA16(a, b, c) __builtin_amdgcn_mfma_f32_16x16x32_bf16((a), (b), (c), 0, 0, 0)

__device__ __forceinline__ short f2b(float f) {
    __hip_bfloat16 h = __float2bfloat16(f);
    return *reinterpret_cast<short*>(&h);
}

// ---------------- ws layout (bytes) ----------------
#define WSO_QATTN 0u                      // float[8192*256]
#define WSO_RES   8388608u                // float[8192*256]
#define WSO_WKT   16777216u               // short[65536]  WkT[o][i]
#define WSO_WVT   16908288u               // short[65536]
#define WSO_G1T   17039360u               // short[65536]
#define WSO_G2T   17170432u               // short[65536]
#define WSO_D2T   17301504u               // short[32768]  d2T[o=256][i=128]
#define WSO_OWT   17367040u               // short[131072] owT[o=512][i=256]

// ================= prep 1: weights -> bf16 transposed =================
extern "C" __global__ __launch_bounds__(256)
void prep_w(const float* __restrict__ Wk, const float* __restrict__ Wv,
            const float* __restrict__ g1w, const float* __restrict__ g2w,
            const float* __restrict__ d2w, const float* __restrict__ ow,
            short* __restrict__ wkT, short* __restrict__ wvT,
            short* __restrict__ g1T, short* __restrict__ g2T,
            short* __restrict__ d2T, short* __restrict__ owT)
{
    const int idx = blockIdx.x * 256 + threadIdx.x;
    if (idx < 65536) {
        const int o = idx >> 8, i = idx & 255;
        wkT[idx] = f2b(Wk[i * 256 + o]);
        wvT[idx] = f2b(Wv[i * 256 + o]);
        g1T[idx] = f2b(g1w[i * 256 + o]);
        g2T[idx] = f2b(g2w[i * 256 + o]);
    }
    if (idx < 32768) {
        const int o = idx >> 7, i = idx & 127;
        d2T[idx] = f2b(d2w[i * 256 + o]);
    }
    if (idx < 131072) {
        const int o = idx >> 8, i = idx & 255;
        owT[idx] = f2b(ow[i * 512 + o]);
    }
}

// ================= prep 2: q_attn = feats_q @ Wq (fp32) + xyz copy =================
extern "C" __global__ __launch_bounds__(256)
void prep_q(const float* __restrict__ feats_q, const float* __restrict__ Wq,
            const float* __restrict__ xyz_q, float* __restrict__ q_attn,
            float* __restrict__ out)
{
    const int b = blockIdx.x;
    const int t = threadIdx.x;
    if (b >= 1024) {                       // 96 blocks: xyz passthrough
        const int idx = (b - 1024) * 256 + t;
        out[idx] = xyz_q[idx];
        return;
    }
    __shared__ float s_q[8][256];
    for (int j = 0; j < 8; ++j)
        s_q[j][t] = feats_q[(size_t)(b * 8 + j) * 256 + t];
    __syncthreads();
    float acc[8] = {0.f, 0.f, 0.f, 0.f, 0.f, 0.f, 0.f, 0.f};
    for (int k = 0; k < 256; ++k) {
        const float wv = Wq[k * 256 + t];
        #pragma unroll
        for (int pt = 0; pt < 8; ++pt) acc[pt] = fmaf(s_q[pt][k], wv, acc[pt]);
    }
    #pragma unroll
    for (int pt = 0; pt < 8; ++pt)
        q_attn[(size_t)(b * 8 + pt) * 256 + t] = acc[pt];
}

// ================= main: per-point fused attention, wave <-> point =================
extern "C" __global__ __launch_bounds__(256, 2)
void ctb_main(const float* __restrict__ xyz_q, const float* __restrict__ xyz_kv,
              const float* __restrict__ feats_kv,
              const float* __restrict__ d1w, const float* __restrict__ d1b,
              const float* __restrict__ d2b, const float* __restrict__ g1b,
              const float* __restrict__ g2b,
              const float* __restrict__ q_attn,
              const short* __restrict__ wkT, const short* __restrict__ wvT,
              const short* __restrict__ g1T, const short* __restrict__ g2T,
              const short* __restrict__ d2T,
              float* __restrict__ res_ws)
{
    __shared__ __align__(16) short s_hb[4][KN][264];   // per-wave h/t buffer, padded
    const int w    = threadIdx.x >> 6;
    const int lane = threadIdx.x & 63;
    const int q    = lane >> 4;          // quad
    const int ln   = lane & 15;
    const int p    = blockIdx.x * 4 + w; // this wave's point

    // ---- r1 = relu(rel @ d1w + d1b) as A-fragments (2 mt x 4 ks), bf16 ----
    bf16x8 a_r1[2][4];
    {
        float q0 = xyz_q[p * 3 + 0], q1 = xyz_q[p * 3 + 1], q2 = xyz_q[p * 3 + 2];
        float rel[2][3];
        #pragma unroll
        for (int mt = 0; mt < 2; ++mt) {
            const int m = 16 * mt + ln;
            const float* xk = xyz_kv + ((size_t)p * KN + m) * 3;
            rel[mt][0] = q0 - xk[0]; rel[mt][1] = q1 - xk[1]; rel[mt][2] = q2 - xk[2];
        }
        #pragma unroll
        for (int ks = 0; ks < 4; ++ks)
            #pragma unroll
            for (int j = 0; j < 8; ++j) {
                const int kd = 32 * ks + 8 * q + j;
                const float w0 = d1w[kd], w1 = d1w[DH + kd], w2 = d1w[2 * DH + kd];
                const float bb = d1b[kd];
                #pragma unroll
                for (int mt = 0; mt < 2; ++mt) {
                    const float v = fmaxf(fmaf(rel[mt][0], w0,
                                          fmaf(rel[mt][1], w1,
                                          fmaf(rel[mt][2], w2, bb))), 0.f);
                    a_r1[mt][ks][j] = f2b(v);
                }
            }
    }

    // ---- feats_kv[p] as A-fragments (2 mt x 8 ks), bf16 ----
    bf16x8 a_f[2][8];
    {
        const float* fp = feats_kv + (size_t)p * KN * DIM;
        #pragma unroll
        for (int mt = 0; mt < 2; ++mt) {
            const int m = 16 * mt + ln;
            #pragma unroll
            for (int ks = 0; ks < 8; ++ks) {
                const float4* src = (const float4*)(fp + m * DIM + 32 * ks + 8 * q);
                const float4 x = src[0], y = src[1];
                bf16x8 tv;
                tv[0] = f2b(x.x); tv[1] = f2b(x.y); tv[2] = f2b(x.z); tv[3] = f2b(x.w);
                tv[4] = f2b(y.x); tv[5] = f2b(y.y); tv[6] = f2b(y.z); tv[7] = f2b(y.w);
                a_f[mt][ks] = tv;
            }
        }
    }

    // ================= phase 1: h = q_attn - k_attn + pos -> LDS =================
    for (int nq = 0; nq < 4; ++nq) {
        const int colbase = 64 * nq + ln;
        f32x4 accp[2][4], acck[2][4];
        #pragma unroll
        for (int nt = 0; nt < 4; ++nt) {
            const int col = colbase + 16 * nt;
            const float init = q_attn[(size_t)p * DIM + col] + d2b[col];
            #pragma unroll
            for (int mt = 0; mt < 2; ++mt) {
                accp[mt][nt] = (f32x4){init, init, init, init};
                acck[mt][nt] = (f32x4){0.f, 0.f, 0.f, 0.f};
            }
        }
        #pragma unroll
        for (int ks = 0; ks < 4; ++ks) {          // pos: K=128
            const short* bp = d2T + 32 * ks + 8 * q;
            #pragma unroll
            for (int nt = 0; nt < 4; ++nt) {
                const bf16x8 bb = *(const bf16x8*)(bp + (colbase + 16 * nt) * DH);
                #pragma unroll
                for (int mt = 0; mt < 2; ++mt)
                    accp[mt][nt] = MFMA16(a_r1[mt][ks], bb, accp[mt][nt]);
            }
        }
        #pragma unroll
        for (int ks = 0; ks < 8; ++ks) {          // k_attn: K=256
            const short* bp = wkT + 32 * ks + 8 * q;
            #pragma unroll
            for (int nt = 0; nt < 4; ++nt) {
                const bf16x8 bb = *(const bf16x8*)(bp + (colbase + 16 * nt) * DIM);
                #pragma unroll
                for (int mt = 0; mt < 2; ++mt)
                    acck[mt][nt] = MFMA16(a_f[mt][ks], bb, acck[mt][nt]);
            }
        }
        #pragma unroll
        for (int mt = 0; mt < 2; ++mt)
            #pragma unroll
            for (int nt = 0; nt < 4; ++nt)
                #pragma unroll
                for (int r = 0; r < 4; ++r) {
                    const int row = 16 * mt + 4 * q + r;
                    const int col = 64 * nq + 16 * nt + ln;
                    s_hb[w][row][col] = f2b(accp[mt][nt][r] - acck[mt][nt][r]);
                }
    }
    __syncthreads();   // scheduling alignment across the 4 independent waves

    // ================= phase 2: t = relu(h @ g1 + g1b) -> LDS (overwrites h) =====
    bf16x8 a_h[2][8];
    #pragma unroll
    for (int mt = 0; mt < 2; ++mt)
        #pragma unroll
        for (int ks = 0; ks < 8; ++ks)
            a_h[mt][ks] = *(const bf16x8*)&s_hb[w][16 * mt + ln][32 * ks + 8 * q];

    for (int nq = 0; nq < 4; ++nq) {
        const int colbase = 64 * nq + ln;
        f32x4 acc[2][4];
        #pragma unroll
        for (int nt = 0; nt < 4; ++nt) {
            const float bb = g1b[colbase + 16 * nt];
            #pragma unroll
            for (int mt = 0; mt < 2; ++mt) acc[mt][nt] = (f32x4){bb, bb, bb, bb};
        }
        #pragma unroll
        for (int ks = 0; ks < 8; ++ks) {
            const short* bp = g1T + 32 * ks + 8 * q;
            #pragma unroll
            for (int nt = 0; nt < 4; ++nt) {
                const bf16x8 bb = *(const bf16x8*)(bp + (colbase + 16 * nt) * DIM);
                #pragma unroll
                for (int mt = 0; mt < 2; ++mt)
                    acc[mt][nt] = MFMA16(a_h[mt][ks], bb, acc[mt][nt]);
            }
        }
        #pragma unroll
        for (int mt = 0; mt < 2; ++mt)
            #pragma unroll
            for (int nt = 0; nt < 4; ++nt)
                #pragma unroll
                for (int r = 0; r < 4; ++r) {
                    const int row = 16 * mt + 4 * q + r;
                    const int col = 64 * nq + 16 * nt + ln;
                    s_hb[w][row][col] = f2b(fmaxf(acc[mt][nt][r], 0.f));
                }
    }
    __syncthreads();

    // ===== phase 3: ap = t@g2+g2b -> softmax_k -> res = sum w*(v_attn+pos) ======
    for (int nq = 0; nq < 4; ++nq) {
        const int colbase = 64 * nq + ln;

        bf16x8 a_t[2][8];
        #pragma unroll
        for (int mt = 0; mt < 2; ++mt)
            #pragma unroll
            for (int ks = 0; ks < 8; ++ks)
                a_t[mt][ks] = *(const bf16x8*)&s_hb[w][16 * mt + ln][32 * ks + 8 * q];

        f32x4 ap[2][4];
        #pragma unroll
        for (int nt = 0; nt < 4; ++nt) {
            const float bb = g2b[colbase + 16 * nt];
            #pragma unroll
            for (int mt = 0; mt < 2; ++mt) ap[mt][nt] = (f32x4){bb, bb, bb, bb};
        }
        #pragma unroll
        for (int ks = 0; ks < 8; ++ks) {
            const short* bp = g2T + 32 * ks + 8 * q;
            #pragma unroll
            for (int nt = 0; nt < 4; ++nt) {
                const bf16x8 bb = *(const bf16x8*)(bp + (colbase + 16 * nt) * DIM);
                #pragma unroll
                for (int mt = 0; mt < 2; ++mt)
                    ap[mt][nt] = MFMA16(a_t[mt][ks], bb, ap[mt][nt]);
            }
        }

        // softmax over neighbors (rows): 8 local values + butterfly over lanes ^16,^32
        float stot[4];
        #pragma unroll
        for (int nt = 0; nt < 4; ++nt) {
            float m = -1e30f;
            #pragma unroll
            for (int mt = 0; mt < 2; ++mt)
                #pragma unroll
                for (int r = 0; r < 4; ++r) m = fmaxf(m, ap[mt][nt][r]);
            m = fmaxf(m, __shfl_xor(m, 16, 64));
            m = fmaxf(m, __shfl_xor(m, 32, 64));
            float s = 0.f;
            #pragma unroll
            for (int mt = 0; mt < 2; ++mt)
                #pragma unroll
                for (int r = 0; r < 4; ++r) {
                    const float e = __expf(ap[mt][nt][r] - m);
                    ap[mt][nt][r] = e;
                    s += e;
                }
            s += __shfl_xor(s, 16, 64);
            s += __shfl_xor(s, 32, 64);
            stot[nt] = s;
        }

        // pos recompute (K=128)
        f32x4 pos[2][4];
        #pragma unroll
        for (int nt = 0; nt < 4; ++nt) {
            const float bb = d2b[colbase + 16 * nt];
            #pragma unroll
            for (int mt = 0; mt < 2; ++mt) pos[mt][nt] = (f32x4){bb, bb, bb, bb};
        }
        #pragma unroll
        for (int ks = 0; ks < 4; ++ks) {
            const short* bp = d2T + 32 * ks + 8 * q;
            #pragma unroll
            for (int nt = 0; nt < 4; ++nt) {
                const bf16x8 bb = *(const bf16x8*)(bp + (colbase + 16 * nt) * DH);
                #pragma unroll
                for (int mt = 0; mt < 2; ++mt)
                    pos[mt][nt] = MFMA16(a_r1[mt][ks], bb, pos[mt][nt]);
            }
        }

        // v_attn (K=256)
        f32x4 vv[2][4];
        #pragma unroll
        for (int nt = 0; nt < 4; ++nt)
            #pragma unroll
            for (int mt = 0; mt < 2; ++mt) vv[mt][nt] = (f32x4){0.f, 0.f, 0.f, 0.f};
        #pragma unroll
        for (int ks = 0; ks < 8; ++ks) {
            const short* bp = wvT + 32 * ks + 8 * q;
            #pragma unroll
            for (int nt = 0; nt < 4; ++nt) {
                const bf16x8 bb = *(const bf16x8*)(bp + (colbase + 16 * nt) * DIM);
                #pragma unroll
                for (int mt = 0; mt < 2; ++mt)
                    vv[mt][nt] = MFMA16(a_f[mt][ks], bb, vv[mt][nt]);
            }
        }

        // weighted sum over rows + butterfly; quad 0 writes res
        #pragma unroll
        for (int nt = 0; nt < 4; ++nt) {
            float r = 0.f;
            #pragma unroll
            for (int mt = 0; mt < 2; ++mt)
                #pragma unroll
                for (int rr = 0; rr < 4; ++rr)
                    r = fmaf(ap[mt][nt][rr], pos[mt][nt][rr] + vv[mt][nt][rr], r);
            r += __shfl_xor(r, 16, 64);
            r += __shfl_xor(r, 32, 64);
            if (q == 0)
                res_ws[(size_t)p * DIM + colbase + 16 * nt] = r / stot[nt];
        }
    }
}

// ================= out: res @ out_w + out_b (MFMA) =================
extern "C" __global__ __launch_bounds__(256, 2)
void ctb_out(const float* __restrict__ res_ws, const short* __restrict__ owT,
             const float* __restrict__ ob, float* __restrict__ out)
{
    __shared__ __align__(16) short s_a[32][264];
    const int t = threadIdx.x, w = t >> 6, lane = t & 63, q = lane >> 4, ln = lane & 15;
    const int rowbase = blockIdx.x * 32;

    {   // stage res rows -> bf16 LDS
        const int row = t >> 3;
        const int c0  = (t & 7) * 32;
        const float* src = res_ws + (size_t)(rowbase + row) * DIM + c0;
        #pragma unroll
        for (int j = 0; j < 32; j += 4) {
            const float4 v = *(const float4*)(src + j);
            s_a[row][c0 + j + 0] = f2b(v.x);
            s_a[row][c0 + j + 1] = f2b(v.y);
            s_a[row][c0 + j + 2] = f2b(v.z);
            s_a[row][c0 + j + 3] = f2b(v.w);
        }
    }
    __syncthreads();

    bf16x8 af[2][8];
    #pragma unroll
    for (int mt = 0; mt < 2; ++mt)
        #pragma unroll
        for (int ks = 0; ks < 8; ++ks)
            af[mt][ks] = *(const bf16x8*)&s_a[16 * mt + ln][32 * ks + 8 * q];

    const int colbase = 128 * w + ln;   // wave owns 128 of 512 cols
    f32x4 acc[2][8];
    #pragma unroll
    for (int nt = 0; nt < 8; ++nt) {
        const float bb = ob[colbase + 16 * nt];
        #pragma unroll
        for (int mt = 0; mt < 2; ++mt) acc[mt][nt] = (f32x4){bb, bb, bb, bb};
    }
    #pragma unroll
    for (int ks = 0; ks < 8; ++ks) {
        const short* bp = owT + 32 * ks + 8 * q;
        #pragma unroll
        for (int nt = 0; nt < 8; ++nt) {
            const bf16x8 bb = *(const bf16x8*)(bp + (colbase + 16 * nt) * DIM);
            #pragma unroll
            for (int mt = 0; mt < 2; ++mt)
                acc[mt][nt] = MFMA16(af[mt][ks], bb, acc[mt][nt]);
        }
    }
    float* o = out + (size_t)NPTS * 3;
    #pragma unroll
    for (int mt = 0; mt < 2; ++mt)
        #pragma unroll
        for (int nt = 0; nt < 8; ++nt)
            #pragma unroll
            for (int r = 0; r < 4; ++r) {
                const int row = 16 * mt + 4 * q + r;
                const int col = colbase + 16 * nt;
                o[(size_t)(rowbase + row) * DOUT + col] = acc[mt][nt][r];
            }
}

// ================= launch =================
extern "C" void kernel_launch(void* const* d_in, const int* in_sizes, int n_in,
                              void* d_out, int out_size, void* d_ws, size_t ws_size,
                              hipStream_t stream) {
    const float* xyz_q    = (const float*)d_in[0];
    const float* feats_q  = (const float*)d_in[1];
    const float* xyz_kv   = (const float*)d_in[2];
    const float* feats_kv = (const float*)d_in[3];
    const float* Wq       = (const float*)d_in[4];
    const float* Wk       = (const float*)d_in[5];
    const float* Wv       = (const float*)d_in[6];
    const float* d1w      = (const float*)d_in[7];
    const float* d1b      = (const float*)d_in[8];
    const float* d2w      = (const float*)d_in[9];
    const float* d2b      = (const float*)d_in[10];
    const float* g1w      = (const float*)d_in[11];
    const float* g1b      = (const float*)d_in[12];
    const float* g2w      = (const float*)d_in[13];
    const float* g2b      = (const float*)d_in[14];
    const float* ow       = (const float*)d_in[15];
    const float* ob       = (const float*)d_in[16];
    float* out = (float*)d_out;

    char* ws = (char*)d_ws;
    float* q_attn = (float*)(ws + WSO_QATTN);
    float* res_ws = (float*)(ws + WSO_RES);
    short* wkT    = (short*)(ws + WSO_WKT);
    short* wvT    = (short*)(ws + WSO_WVT);
    short* g1T    = (short*)(ws + WSO_G1T);
    short* g2T    = (short*)(ws + WSO_G2T);
    short* d2T    = (short*)(ws + WSO_D2T);
    short* owT    = (short*)(ws + WSO_OWT);

    prep_w<<<dim3(512), dim3(256), 0, stream>>>(Wk, Wv, g1w, g2w, d2w, ow,
                                                wkT, wvT, g1T, g2T, d2T, owT);
    prep_q<<<dim3(1120), dim3(256), 0, stream>>>(feats_q, Wq, xyz_q, q_attn, out);
    ctb_main<<<dim3(2048), dim3(256), 0, stream>>>(
        xyz_q, xyz_kv, feats_kv, d1w, d1b, d2b, g1b, g2b,
        q_attn, wkT, wvT, g1T, g2T, d2T, res_ws);
    ctb_out<<<dim3(256), dim3(256), 0, stream>>>(res_ws, owT, ob, out);
}